// Round 1
// baseline (292.529 us; speedup 1.0000x reference)
//
#include <hip/hip_runtime.h>

#define IMG_H 512
#define IMG_W 512
#define N_IMG 24              // B*C = 8*3
#define NPIX (N_IMG * IMG_H * IMG_W)   // 6291456
#define STRIPS_PER_ROW (IMG_W / 4)     // 128
#define NSTRIPS (NPIX / 4)             // 1572864
#define BLOCK 256
#define NBLOCKS (NSTRIPS / BLOCK)      // 6144

__device__ __forceinline__ int reflect_idx(int x, int n) {
    // jnp.pad mode='reflect': x<0 -> -x ; x>=n -> 2n-2-x  (PAD=2 so single bounce)
    if (x < 0) return -x;
    if (x >= n) return 2 * n - 2 - x;
    return x;
}

__global__ void census_init(unsigned int* __restrict__ ws) {
    ws[0] = 0u;  // hamming sum
    ws[1] = 0u;  // blocks-done counter
}

__global__ __launch_bounds__(BLOCK) void census_main(
    const float* __restrict__ pred, const float* __restrict__ gt,
    float* __restrict__ out, unsigned int* __restrict__ ws)
{
    const int s = blockIdx.x * BLOCK + threadIdx.x;   // strip id, exact cover
    const int w0   = (s & (STRIPS_PER_ROW - 1)) * 4;
    const int rest = s >> 7;             // / 128
    const int h    = rest & (IMG_H - 1);
    const int img  = rest >> 9;          // / 512

    const float* __restrict__ pimg = pred + (size_t)img * IMG_H * IMG_W;
    const float* __restrict__ gimg = gt   + (size_t)img * IMG_H * IMG_W;

    // center pixels: columns w0..w0+3 of row h (16B aligned)
    float pc[4], gc[4];
    {
        float4 p4 = *(const float4*)(pimg + h * IMG_W + w0);
        float4 g4 = *(const float4*)(gimg + h * IMG_W + w0);
        pc[0] = p4.x; pc[1] = p4.y; pc[2] = p4.z; pc[3] = p4.w;
        gc[0] = g4.x; gc[1] = g4.y; gc[2] = g4.z; gc[3] = g4.w;
    }

    const bool interior_w = (w0 >= 4) && (w0 <= IMG_W - 8);
    int cnt = 0;

    #pragma unroll
    for (int dy = -2; dy <= 2; ++dy) {
        const int ry = reflect_idx(h + dy, IMG_H);   // wave-uniform branch
        const float* __restrict__ pr = pimg + ry * IMG_W;
        const float* __restrict__ gr = gimg + ry * IMG_W;

        float p[8], g[8];   // columns w0-2 .. w0+5
        if (interior_w) {
            const float2* pp2 = (const float2*)(pr + w0 - 2);  // 8B aligned
            const float2* gg2 = (const float2*)(gr + w0 - 2);
            float2 a0 = pp2[0], a1 = pp2[1], a2 = pp2[2], a3 = pp2[3];
            p[0]=a0.x; p[1]=a0.y; p[2]=a1.x; p[3]=a1.y;
            p[4]=a2.x; p[5]=a2.y; p[6]=a3.x; p[7]=a3.y;
            float2 b0 = gg2[0], b1 = gg2[1], b2 = gg2[2], b3 = gg2[3];
            g[0]=b0.x; g[1]=b0.y; g[2]=b1.x; g[3]=b1.y;
            g[4]=b2.x; g[5]=b2.y; g[6]=b3.x; g[7]=b3.y;
        } else {
            #pragma unroll
            for (int k = 0; k < 8; ++k) {
                int c = reflect_idx(w0 - 2 + k, IMG_W);
                p[k] = pr[c];
                g[k] = gr[c];
            }
        }

        // 4 pixels x 5 dx offsets (skip center-of-window)
        #pragma unroll
        for (int k = 0; k < 4; ++k) {
            #pragma unroll
            for (int dx = -2; dx <= 2; ++dx) {
                if (dy == 0 && dx == 0) continue;
                bool pb = p[k + 2 + dx] < pc[k];
                bool gb = g[k + 2 + dx] < gc[k];
                cnt += (pb != gb) ? 1 : 0;
            }
        }
    }

    // ---- block reduction (int, exact) ----
    #pragma unroll
    for (int off = 32; off > 0; off >>= 1)
        cnt += __shfl_down(cnt, off, 64);

    __shared__ int wave_sums[BLOCK / 64];
    const int lane = threadIdx.x & 63;
    const int wid  = threadIdx.x >> 6;
    if (lane == 0) wave_sums[wid] = cnt;
    __syncthreads();

    if (threadIdx.x == 0) {
        int total = wave_sums[0] + wave_sums[1] + wave_sums[2] + wave_sums[3];
        atomicAdd(&ws[0], (unsigned int)total);
        __threadfence();
        unsigned int r = atomicAdd(&ws[1], 1u);
        if (r == (unsigned int)(NBLOCKS - 1)) {
            unsigned int tot = atomicAdd(&ws[0], 0u);  // coherent read
            out[0] = (float)((double)tot / (double)NPIX);
        }
    }
}

extern "C" void kernel_launch(void* const* d_in, const int* in_sizes, int n_in,
                              void* d_out, int out_size, void* d_ws, size_t ws_size,
                              hipStream_t stream) {
    const float* pred = (const float*)d_in[0];
    const float* gt   = (const float*)d_in[1];
    float* out = (float*)d_out;
    unsigned int* ws = (unsigned int*)d_ws;

    census_init<<<1, 1, 0, stream>>>(ws);
    census_main<<<NBLOCKS, BLOCK, 0, stream>>>(pred, gt, out, ws);
}

// Round 3
// 132.496 us; speedup vs baseline: 2.2078x; 2.2078x over previous
//
#include <hip/hip_runtime.h>

#define IMG_H 512
#define IMG_W 512
#define N_IMG 24                        // B*C
#define NPIX (N_IMG * IMG_H * IMG_W)    // 6291456
#define ROWS_PT 8                       // rows per thread
#define SLABS (IMG_H / ROWS_PT)         // 64
#define SCOLS (IMG_W / 4)               // 128 strip-columns
#define BLOCK 256
#define NTHREADS (N_IMG * SLABS * SCOLS) // 196608
#define NBLOCKS (NTHREADS / BLOCK)       // 768

__device__ __forceinline__ int reflect_idx(int x, int n) {
    // jnp.pad 'reflect', PAD=2 -> single bounce
    if (x < 0) return -x;
    if (x >= n) return 2 * n - 2 - x;
    return x;
}

// Load the 8-float window (cols w0-2 .. w0+5, reflect-padded) of one row.
// Two dwordx4 loads at branchless clamped IN-BOUNDS addresses; edge fixup is
// pure register permutes. aL in [0,506], aR in [2,508] -> never OOB.
__device__ __forceinline__ void load_row(const float* __restrict__ row, int w0,
                                         float w[8]) {
    const int aL = (w0 == 0) ? 0 : ((w0 == 508) ? 506 : (w0 - 2));
    const int aR = (w0 == 0) ? 2 : ((w0 == 508) ? 508 : (w0 + 2));
    float4 A = *(const float4*)(row + aL);
    float4 B = *(const float4*)(row + aR);
    // interior: A = cols w0-2..w0+1, B = cols w0+2..w0+5
    w[0] = A.x; w[1] = A.y; w[2] = A.z; w[3] = A.w;
    w[4] = B.x; w[5] = B.y; w[6] = B.z; w[7] = B.w;
    if (w0 == 0) {
        // A = cols 0..3, B = cols 2..5 ; window [-2..5] -> [2,1,0,1,2,3,4,5]
        w[0] = A.z; w[1] = A.y; w[2] = A.x; w[3] = A.y;
        w[4] = A.z; w[5] = A.w; w[6] = B.z; w[7] = B.w;
    } else if (w0 == 508) {
        // A = 506..509, B = 508..511 ; window [506..513] -> [506..511, 510, 509]
        w[4] = B.z; w[5] = B.w; w[6] = B.z; w[7] = B.y;
    }
}

__global__ void census_init(unsigned int* __restrict__ ws) {
    ws[0] = 0u;
    ws[1] = 0u;
}

__global__ __launch_bounds__(BLOCK) void census_main(
    const float* __restrict__ pred, const float* __restrict__ gt,
    float* __restrict__ out, unsigned int* __restrict__ ws)
{
    const int t    = blockIdx.x * BLOCK + threadIdx.x;
    const int sc   = t & (SCOLS - 1);        // strip column (consecutive lanes)
    const int rest = t >> 7;
    const int slab = rest & (SLABS - 1);
    const int img  = rest >> 6;
    const int w0   = sc * 4;
    const int h0   = slab * ROWS_PT;

    const float* __restrict__ pimg = pred + (size_t)img * IMG_H * IMG_W;
    const float* __restrict__ gimg = gt   + (size_t)img * IMG_H * IMG_W;

    // rolling 5-row window of 8-col strips, both inputs
    float pw[5][8], gw[5][8];

    #pragma unroll
    for (int i = 0; i < 4; ++i) {   // rows h0-2 .. h0+1 -> slots 0..3
        const int ry = reflect_idx(h0 - 2 + i, IMG_H);
        load_row(pimg + ry * IMG_W, w0, pw[i]);
        load_row(gimg + ry * IMG_W, w0, gw[i]);
    }

    int cnt = 0;

    #pragma unroll
    for (int r = 0; r < ROWS_PT; ++r) {
        // bring in row h0+r+2 -> slot (r+4)%5  (the dy=+2 row)
        const int ry = reflect_idx(h0 + r + 2, IMG_H);
        load_row(pimg + ry * IMG_W, w0, pw[(r + 4) % 5]);
        load_row(gimg + ry * IMG_W, w0, gw[(r + 4) % 5]);

        const int c = (r + 2) % 5;   // center row slot
        const float pc0 = pw[c][2], pc1 = pw[c][3], pc2 = pw[c][4], pc3 = pw[c][5];
        const float gc0 = gw[c][2], gc1 = gw[c][3], gc2 = gw[c][4], gc3 = gw[c][5];

        #pragma unroll
        for (int dy = 0; dy < 5; ++dy) {
            const int wr = (r + dy) % 5;
            #pragma unroll
            for (int dx = 0; dx < 5; ++dx) {
                if (dy == 2 && dx == 2) continue;   // center of window
                cnt += (int)((pw[wr][0 + dx] < pc0) != (gw[wr][0 + dx] < gc0));
                cnt += (int)((pw[wr][1 + dx] < pc1) != (gw[wr][1 + dx] < gc1));
                cnt += (int)((pw[wr][2 + dx] < pc2) != (gw[wr][2 + dx] < gc2));
                cnt += (int)((pw[wr][3 + dx] < pc3) != (gw[wr][3 + dx] < gc3));
            }
        }
    }

    // ---- exact integer reduction ----
    #pragma unroll
    for (int off = 32; off > 0; off >>= 1)
        cnt += __shfl_down(cnt, off, 64);

    __shared__ int wave_sums[BLOCK / 64];
    const int lane = threadIdx.x & 63;
    const int wid  = threadIdx.x >> 6;
    if (lane == 0) wave_sums[wid] = cnt;
    __syncthreads();

    if (threadIdx.x == 0) {
        int total = wave_sums[0] + wave_sums[1] + wave_sums[2] + wave_sums[3];
        atomicAdd(&ws[0], (unsigned int)total);
        __threadfence();
        unsigned int r = atomicAdd(&ws[1], 1u);
        if (r == (unsigned int)(NBLOCKS - 1)) {
            unsigned int tot = atomicAdd(&ws[0], 0u);
            out[0] = (float)((double)tot / (double)NPIX);
        }
    }
}

extern "C" void kernel_launch(void* const* d_in, const int* in_sizes, int n_in,
                              void* d_out, int out_size, void* d_ws, size_t ws_size,
                              hipStream_t stream) {
    const float* pred = (const float*)d_in[0];
    const float* gt   = (const float*)d_in[1];
    float* out        = (float*)d_out;
    unsigned int* ws  = (unsigned int*)d_ws;

    census_init<<<1, 1, 0, stream>>>(ws);
    census_main<<<NBLOCKS, BLOCK, 0, stream>>>(pred, gt, out, ws);
}